// Round 13
// baseline (260.625 us; speedup 1.0000x reference)
//
#include <hip/hip_runtime.h>

#define KH_   10
#define KW_   4
#define W_    64
#define K1_   5120       // C*KH*KW
#define WK_   61
#define JP_   5824       // 91*64
#define NZ    819200
#define KS1   8          // k-split gemm1 (chunk 640, 20 iters of 32; M-split x2)
#define KS2   8          // jp-split gemm2 (chunk ~23 iters of 32)

typedef __attribute__((ext_vector_type(8))) short short8;
typedef __attribute__((ext_vector_type(4))) short short4v;
typedef __attribute__((ext_vector_type(4))) float f32x4;

__device__ __forceinline__ unsigned short f2bf(float f) {
    unsigned int u = __float_as_uint(f);
    return (unsigned short)((u + 0x8000u) >> 16);
}

// ---------------------------------------------------------------------------
// pack: Qb2 (Q frag layout) + X (gemm1 B) + zero the 80 gemm2 dt-group
// counters (tids 921600..921679; stream order makes them visible to gemm2).
// ---------------------------------------------------------------------------
__global__ __launch_bounds__(256) void pack_kernel(const float* __restrict__ z1,
                                                   const float* __restrict__ z2,
                                                   unsigned short* __restrict__ Qb2,
                                                   unsigned short* __restrict__ X,
                                                   unsigned* __restrict__ cnt) {
    int tid = blockIdx.x * 256 + threadIdx.x;   // < 921856
    if (tid >= 921600) {                      // --- counter zeroing ---
        int o = tid - 921600;
        if (o < 80) cnt[o] = 0u;
        return;
    }
    if (tid < 102400) {                       // --- Qb2 octs (frag layout) ---
        int ko = tid / 160, i = tid - ko * 160;
        int d0 = ko * 8;
        int c = d0 / 40, rr = d0 - c * 40;
        int kh0 = rr >> 2;                    // even
        int ih = i >> 4, iw = i & 15;
        int a0 = c * 6400 + (ih * KH_ + kh0) * W_ + iw * KW_;
        unsigned short v[8];
#pragma unroll
        for (int s = 0; s < 4; ++s) v[s] = f2bf(z1[a0 + s]);
#pragma unroll
        for (int s = 0; s < 4; ++s) v[4 + s] = f2bf(z1[a0 + W_ + s]);
        *(short8*)(Qb2 + (size_t)tid * 8) = *(short8*)v;
    } else {                                  // --- X octs ---
        int o = tid - 102400;                 // o = (c*100+h)*64 + w
        int w = o & 63, ch = o >> 6;
        int h = ch % 100;
        unsigned short v[8];
        if (w <= 60 && h < 99) {              // fast path: no clamping needed
            const float* p0 = z2 + ch * 64 + w;
#pragma unroll
            for (int s = 0; s < 4; ++s) v[s] = f2bf(p0[s]);
#pragma unroll
            for (int s = 0; s < 4; ++s) v[4 + s] = f2bf(p0[64 + s]);
        } else {                              // boundary path (w>60 or h==99)
            int ch2 = (h < 99) ? ch + 1 : ch;
#pragma unroll
            for (int s = 0; s < 4; ++s) v[s] = f2bf(z2[ch * 64 + min(w + s, 63)]);
#pragma unroll
            for (int s = 0; s < 4; ++s) v[4 + s] = f2bf(z2[ch2 * 64 + min(w + s, 63)]);
        }
        *(short8*)(X + (size_t)o * 8) = *(short8*)v;
    }
}

// ---------------------------------------------------------------------------
// GEMM1: no LDS, no barriers. grid (KS1=8, 92) = 736 blocks x 256 thr.
// Block tile 80(m) x 128(j) x 640(k); wave tile 80x32 (acc[5][2]).
// (identical to the measured 128.5us R10 version)
// ---------------------------------------------------------------------------
__global__ __launch_bounds__(256) void gemm1_kernel(const unsigned short* __restrict__ Qb2,
                                                    const unsigned short* __restrict__ X,
                                                    float* __restrict__ Sp) {
    const int t = threadIdx.x;
    const int ksp = blockIdx.x;      // 0..7
    const int by  = blockIdx.y;      // 0..91
    const int hkt = by >> 1;         // 0..45
    const int mhf = by & 1;          // row half (80 rows each)
    const int hk0 = hkt * 2;
    const int wave = t >> 6, lane = t & 63;
    const int nh = wave;             // 0..3: 32-col strip within 128
    const int l15 = lane & 15, q = lane >> 4;

    int band[2], wk[2];
#pragma unroll
    for (int n = 0; n < 2; ++n) {
        int jpn = nh * 32 + n * 16 + l15;
        band[n] = jpn >> 6;
        wk[n]   = jpn & 63;
    }
    int rowA[5];
#pragma unroll
    for (int b = 0; b < 5; ++b) rowA[b] = mhf * 80 + b * 16 + l15;

    f32x4 acc[5][2];
#pragma unroll
    for (int b = 0; b < 5; ++b)
#pragma unroll
        for (int n = 0; n < 2; ++n) acc[b][n] = (f32x4){0.f, 0.f, 0.f, 0.f};

    for (int it = 0; it < 20; ++it) {
        const unsigned short* Ab = Qb2 + ((size_t)(ksp * 80 + it * 4 + q) * 160) * 8;
        short8 af[5], bf[2];
#pragma unroll
        for (int b = 0; b < 5; ++b)
            af[b] = *(const short8*)(Ab + rowA[b] * 8);
        int d0 = ksp * 640 + it * 32 + q * 8;
        unsigned du = (unsigned)d0;
        int c = du / 40u, rr = d0 - c * 40;
        int kh0 = rr >> 2;           // even
        const unsigned short* Bb = X + ((size_t)(c * 100 + hk0 + kh0) * 64) * 8;
#pragma unroll
        for (int n = 0; n < 2; ++n)
            bf[n] = *(const short8*)(Bb + (band[n] * 64 + wk[n]) * 8);
#pragma unroll
        for (int b = 0; b < 5; ++b)
#pragma unroll
            for (int n = 0; n < 2; ++n)
                acc[b][n] = __builtin_amdgcn_mfma_f32_16x16x32_bf16(af[b], bf[n], acc[b][n], 0, 0, 0);
    }
    float* base = Sp + (size_t)ksp * (160 * JP_);
#pragma unroll
    for (int b = 0; b < 5; ++b) {
        int i0 = mhf * 80 + b * 16 + q * 4;
#pragma unroll
        for (int n = 0; n < 2; ++n) {
            int jg = hkt * 128 + nh * 32 + n * 16 + l15;
            if (jg < JP_) {
#pragma unroll
                for (int r = 0; r < 4; ++r)
                    base[(size_t)(i0 + r) * JP_ + jg] = acc[b][n][r];
            }
        }
    }
}

// ---------------------------------------------------------------------------
// smpz: softmax (blocks 0..159, one q-row each, 512 thr) + Z2s packing
// (blocks 160..959) — independent work filling the CUs softmax leaves idle.
// (identical to the measured 128.5us R10 version)
// ---------------------------------------------------------------------------
__global__ __launch_bounds__(512) void smpz_kernel(const float* __restrict__ z2,
                                                   const float* __restrict__ Sp,
                                                   unsigned short* __restrict__ Atn2,
                                                   unsigned short* __restrict__ Z2s) {
    const int bid = blockIdx.x;
    const int t = threadIdx.x;
    if (bid < 160) {                          // ---- softmax role ----
        const int i = bid;
        const int wave = t >> 6, lane = t & 63;
        __shared__ float red2[8];
        f32x4 v[3];
        float s = 0.f;
#pragma unroll
        for (int jj = 0; jj < 3; ++jj) {
            int q4 = t + jj * 512;
            f32x4 r = (f32x4){0.f, 0.f, 0.f, 0.f};
            if (q4 < 1456) {
                f32x4 a = (f32x4){0.f, 0.f, 0.f, 0.f};
#pragma unroll
                for (int p = 0; p < KS1; ++p)
                    a += *(const f32x4*)(Sp + (size_t)p * (160 * JP_) + (size_t)i * JP_ + q4 * 4);
                a *= (1.0f / 5120.0f);
                bool pad_hi = (((q4 * 4) & 63) == 60);   // cols 61,62,63 of a band
#pragma unroll
                for (int e = 0; e < 4; ++e) {
                    bool ok = !(pad_hi && e > 0);
                    float x = ok ? __expf(a[e]) : 0.f;
                    r[e] = x;
                    s += x;
                }
            }
            v[jj] = r;
        }
#pragma unroll
        for (int off = 32; off >= 1; off >>= 1) s += __shfl_xor(s, off);
        if (lane == 0) red2[wave] = s;
        __syncthreads();
        float inv = 1.0f / (red2[0] + red2[1] + red2[2] + red2[3] +
                            red2[4] + red2[5] + red2[6] + red2[7]);
#pragma unroll
        for (int jj = 0; jj < 3; ++jj) {
            int q4 = t + jj * 512;
            if (q4 < 1456) {
                short4v u;
                u.x = (short)f2bf(v[jj].x * inv);
                u.y = (short)f2bf(v[jj].y * inv);
                u.z = (short)f2bf(v[jj].z * inv);
                u.w = (short)f2bf(v[jj].w * inv);
                *(short4v*)(Atn2 + ((size_t)(q4 >> 1) * 160 + i) * 8 + (q4 & 1) * 4) = u;
            }
        }
    } else {                                  // ---- Z2s-pack role ----
        int o = (bid - 160) * 512 + t;        // 0..409599
        int kw = o / 102400, r8 = o - kw * 102400;
        int e0 = r8 * 8;
        int w0 = e0 & 63, rowbase = e0 - w0;
        unsigned short v[8];
        if (w0 < 56 || kw == 0) {             // fast path: window fits in row
            const float* p = z2 + rowbase + w0 + kw;
#pragma unroll
            for (int s = 0; s < 8; ++s) v[s] = f2bf(p[s]);
        } else {                              // boundary: clamp at col 63
#pragma unroll
            for (int s = 0; s < 8; ++s) v[s] = f2bf(z2[rowbase + min(w0 + s + kw, 63)]);
        }
        *(short8*)(Z2s + (size_t)kw * NZ + e0) = *(short8*)v;
    }
}

// ---------------------------------------------------------------------------
// GEMM2 + fused reduce: grid (KS2=8, 80); tile 64(d) x 160(i), dbuf LDS.
// Epilogue: store Op partial, release-fence + atomicAdd(cnt[dt]); the 8th
// (last) arriver of each dt-group acquire-fences, folds the 8 partials and
// scatters to out — split-K last-block-done pattern, no spinning (R8 lesson).
// ---------------------------------------------------------------------------
__global__ __launch_bounds__(256) void gemm2_kernel(const unsigned short* __restrict__ Atn2,
                                                    const unsigned short* __restrict__ Z2s,
                                                    float* __restrict__ Op,
                                                    float* __restrict__ out,
                                                    unsigned* __restrict__ cnt) {
    __shared__ short As[2][64 * 40];   // KV^T tile [d_local][jp_local], stride 40 (2-way, free)
    const int t = threadIdx.x;
    const int ksp = blockIdx.x;      // 0..7
    const int dt = blockIdx.y;       // 0..79
    const int dbase = dt * 64;
    const int it0 = (182 * ksp) >> 3;
    const int it1 = (182 * (ksp + 1)) >> 3;
    const int wave = t >> 6, lane = t & 63;
    const int mh = wave & 1, nh = wave >> 1;       // wave tile 32(d) x 80(i)
    const int l15 = lane & 15, q = lane >> 4;

    // staging geometry (one short8 per thread per k-iter)
    const int dl_s = t >> 2, jg_s = t & 3;
    const int d_s = dbase + dl_s;
    const unsigned du_s = (unsigned)d_s;
    const int c_s = du_s / 40u, rr_s = d_s - c_s * 40;
    const int kh_s = rr_s >> 2, kw_s = rr_s & 3;
    const int sbase = kw_s * NZ + c_s * 6400 + kh_s * W_;

    f32x4 acc[2][5];
#pragma unroll
    for (int m = 0; m < 2; ++m)
#pragma unroll
        for (int n = 0; n < 5; ++n) acc[m][n] = (f32x4){0.f, 0.f, 0.f, 0.f};

#define STAGE2(buf, itv) do {                                                  \
        int jp0_ = (itv) * 32 + jg_s * 8;                                      \
        int hk_ = jp0_ >> 6, wk0_ = jp0_ & 63;                                 \
        *(short8*)&As[buf][dl_s * 40 + jg_s * 8] =                             \
            *(const short8*)(Z2s + sbase + hk_ * W_ + wk0_);                   \
    } while (0)

    STAGE2(0, it0);
    for (int it = it0; it < it1; ++it) {
        int pb = (it - it0) & 1;
        __syncthreads();                       // As[pb] ready
        if (it + 1 < it1) STAGE2(pb ^ 1, it + 1);
        int k0 = it * 32;
        short8 af[2], bf[5];
#pragma unroll
        for (int m = 0; m < 2; ++m)
            af[m] = *(const short8*)&As[pb][(mh * 32 + m * 16 + l15) * 40 + q * 8];
        const unsigned short* Bb = Atn2 + ((size_t)((k0 >> 3) + q) * 160) * 8;
#pragma unroll
        for (int n = 0; n < 5; ++n)
            bf[n] = *(const short8*)(Bb + ((nh * 5 + n) * 16 + l15) * 8);
#pragma unroll
        for (int m = 0; m < 2; ++m)
#pragma unroll
            for (int n = 0; n < 5; ++n)
                acc[m][n] = __builtin_amdgcn_mfma_f32_16x16x32_bf16(af[m], bf[n], acc[m][n], 0, 0, 0);
    }
#undef STAGE2

    float* base = Op + (size_t)ksp * ((size_t)NZ);
#pragma unroll
    for (int m = 0; m < 2; ++m) {
        int d0 = dbase + mh * 32 + m * 16 + q * 4;
#pragma unroll
        for (int n = 0; n < 5; ++n) {
            int i = (nh * 5 + n) * 16 + l15;
#pragma unroll
            for (int r = 0; r < 4; ++r)
                base[(size_t)(d0 + r) * 160 + i] = acc[m][n][r];
        }
    }

    // ---- fused reduce: last arriver of this dt-group folds the partials ----
    __threadfence();                          // release: Op stores visible agent-wide
    __shared__ unsigned lastdone;
    if (t == 0) lastdone = atomicAdd(&cnt[dt], 1u);   // device-scope by default
    __syncthreads();
    if (lastdone == KS2 - 1) {
        __threadfence();                      // acquire: other blocks' Op visible
        for (int r8 = t; r8 < 2560; r8 += 256) {      // 64d x 160i / 4
            int f = dbase * 160 + r8 * 4;
            f32x4 s = (f32x4){0.f, 0.f, 0.f, 0.f};
#pragma unroll
            for (int p = 0; p < KS2; ++p) s += *(const f32x4*)(Op + (size_t)p * NZ + f);
            int d = f / 160, i0 = f - d * 160;        // x4 never straddles d
            int c = d / 40, rr = d - c * 40;
            int kh = rr >> 2, kw = rr & 3;
#pragma unroll
            for (int r = 0; r < 4; ++r) {
                int i = i0 + r;
                int ih = i >> 4, iw = i & 15;
                out[c * 6400 + (ih * KH_ + kh) * W_ + iw * KW_ + kw] = s[r];
            }
        }
    }
}

extern "C" void kernel_launch(void* const* d_in, const int* in_sizes, int n_in,
                              void* d_out, int out_size, void* d_ws, size_t ws_size,
                              hipStream_t stream) {
    const float* z1 = (const float*)d_in[0];
    const float* z2 = (const float*)d_in[1];
    float* out = (float*)d_out;

    char* w = (char*)d_ws;
    unsigned short* Qb2  = (unsigned short*)(w);                 // 1,638,400 B
    unsigned short* Z2s  = (unsigned short*)(w + 1638400);       // 6,553,600 B
    unsigned short* X    = (unsigned short*)(w + 8192000);       // 13,107,200 B
    unsigned short* Atn2 = (unsigned short*)(w + 21299200);      // 1,863,680 B
    float* Sp = (float*)(w + 23162880);                          // 29,818,880 B (8 partials)
    float* Op = (float*)(w + 52981760);                          // 26,214,400 B (8 partials)
    unsigned* cnt = (unsigned*)(w + 79196160);                   // 320 B dt-group counters

    pack_kernel<<<3601, 256, 0, stream>>>(z1, z2, Qb2, X, cnt);
    gemm1_kernel<<<dim3(KS1, 92), 256, 0, stream>>>(Qb2, X, Sp);
    smpz_kernel<<<960, 512, 0, stream>>>(z2, Sp, Atn2, Z2s);
    gemm2_kernel<<<dim3(KS2, 80), 256, 0, stream>>>(Atn2, Z2s, Op, out, cnt);
}

// Round 14
// 137.529 us; speedup vs baseline: 1.8951x; 1.8951x over previous
//
#include <hip/hip_runtime.h>

#define KH_   10
#define KW_   4
#define W_    64
#define K1_   5120       // C*KH*KW
#define WK_   61
#define JP_   5824       // 91*64
#define NZ    819200
#define KS1   16         // k-split gemm1 (chunk 320, 10 iters of 32; M-split x2)
#define KS2   16         // jp-split gemm2 (~11 iters of 32)

typedef __attribute__((ext_vector_type(8))) short short8;
typedef __attribute__((ext_vector_type(4))) short short4v;
typedef __attribute__((ext_vector_type(4))) float f32x4;

__device__ __forceinline__ unsigned short f2bf(float f) {
    unsigned int u = __float_as_uint(f);
    return (unsigned short)((u + 0x8000u) >> 16);
}

// ---------------------------------------------------------------------------
// pack: Qb2 (Q frag layout) + X (gemm1 B).  (identical to measured R10)
// ---------------------------------------------------------------------------
__global__ __launch_bounds__(256) void pack_kernel(const float* __restrict__ z1,
                                                   const float* __restrict__ z2,
                                                   unsigned short* __restrict__ Qb2,
                                                   unsigned short* __restrict__ X) {
    int tid = blockIdx.x * 256 + threadIdx.x;   // < 921600
    if (tid < 102400) {                       // --- Qb2 octs (frag layout) ---
        int ko = tid / 160, i = tid - ko * 160;
        int d0 = ko * 8;
        int c = d0 / 40, rr = d0 - c * 40;
        int kh0 = rr >> 2;                    // even
        int ih = i >> 4, iw = i & 15;
        int a0 = c * 6400 + (ih * KH_ + kh0) * W_ + iw * KW_;
        unsigned short v[8];
#pragma unroll
        for (int s = 0; s < 4; ++s) v[s] = f2bf(z1[a0 + s]);
#pragma unroll
        for (int s = 0; s < 4; ++s) v[4 + s] = f2bf(z1[a0 + W_ + s]);
        *(short8*)(Qb2 + (size_t)tid * 8) = *(short8*)v;
    } else {                                  // --- X octs ---
        int o = tid - 102400;                 // o = (c*100+h)*64 + w
        int w = o & 63, ch = o >> 6;
        int h = ch % 100;
        unsigned short v[8];
        if (w <= 60 && h < 99) {              // fast path: no clamping needed
            const float* p0 = z2 + ch * 64 + w;
#pragma unroll
            for (int s = 0; s < 4; ++s) v[s] = f2bf(p0[s]);
#pragma unroll
            for (int s = 0; s < 4; ++s) v[4 + s] = f2bf(p0[64 + s]);
        } else {                              // boundary path (w>60 or h==99)
            int ch2 = (h < 99) ? ch + 1 : ch;
#pragma unroll
            for (int s = 0; s < 4; ++s) v[s] = f2bf(z2[ch * 64 + min(w + s, 63)]);
#pragma unroll
            for (int s = 0; s < 4; ++s) v[4 + s] = f2bf(z2[ch2 * 64 + min(w + s, 63)]);
        }
        *(short8*)(X + (size_t)o * 8) = *(short8*)v;
    }
}

// ---------------------------------------------------------------------------
// GEMM1: no LDS, no barriers. grid (KS1=16, 92) = 1472 blocks x 256 thr
// (5.75 blocks/CU = 23 waves/CU — 2x the TLP of the measured R10 config;
// R13 attribution shows both GEMMs latency-bound at 2.5-2.9 blocks/CU).
// Block tile 80(m) x 128(j) x 320(k), 10 iters; wave tile 80x32 (acc[5][2]).
// ---------------------------------------------------------------------------
__global__ __launch_bounds__(256) void gemm1_kernel(const unsigned short* __restrict__ Qb2,
                                                    const unsigned short* __restrict__ X,
                                                    float* __restrict__ Sp) {
    const int t = threadIdx.x;
    const int ksp = blockIdx.x;      // 0..15
    const int by  = blockIdx.y;      // 0..91
    const int hkt = by >> 1;         // 0..45
    const int mhf = by & 1;          // row half (80 rows each)
    const int hk0 = hkt * 2;
    const int wave = t >> 6, lane = t & 63;
    const int nh = wave;             // 0..3: 32-col strip within 128
    const int l15 = lane & 15, q = lane >> 4;

    int band[2], wk[2];
#pragma unroll
    for (int n = 0; n < 2; ++n) {
        int jpn = nh * 32 + n * 16 + l15;
        band[n] = jpn >> 6;
        wk[n]   = jpn & 63;
    }
    int rowA[5];
#pragma unroll
    for (int b = 0; b < 5; ++b) rowA[b] = mhf * 80 + b * 16 + l15;

    f32x4 acc[5][2];
#pragma unroll
    for (int b = 0; b < 5; ++b)
#pragma unroll
        for (int n = 0; n < 2; ++n) acc[b][n] = (f32x4){0.f, 0.f, 0.f, 0.f};

    for (int it = 0; it < 10; ++it) {
        const unsigned short* Ab = Qb2 + ((size_t)(ksp * 40 + it * 4 + q) * 160) * 8;
        short8 af[5], bf[2];
#pragma unroll
        for (int b = 0; b < 5; ++b)
            af[b] = *(const short8*)(Ab + rowA[b] * 8);
        int d0 = ksp * 320 + it * 32 + q * 8;
        unsigned du = (unsigned)d0;
        int c = du / 40u, rr = d0 - c * 40;
        int kh0 = rr >> 2;           // even
        const unsigned short* Bb = X + ((size_t)(c * 100 + hk0 + kh0) * 64) * 8;
#pragma unroll
        for (int n = 0; n < 2; ++n)
            bf[n] = *(const short8*)(Bb + (band[n] * 64 + wk[n]) * 8);
#pragma unroll
        for (int b = 0; b < 5; ++b)
#pragma unroll
            for (int n = 0; n < 2; ++n)
                acc[b][n] = __builtin_amdgcn_mfma_f32_16x16x32_bf16(af[b], bf[n], acc[b][n], 0, 0, 0);
    }
    float* base = Sp + (size_t)ksp * (160 * JP_);
#pragma unroll
    for (int b = 0; b < 5; ++b) {
        int i0 = mhf * 80 + b * 16 + q * 4;
#pragma unroll
        for (int n = 0; n < 2; ++n) {
            int jg = hkt * 128 + nh * 32 + n * 16 + l15;
            if (jg < JP_) {
#pragma unroll
                for (int r = 0; r < 4; ++r)
                    base[(size_t)(i0 + r) * JP_ + jg] = acc[b][n][r];
            }
        }
    }
}

// ---------------------------------------------------------------------------
// smpz: softmax (blocks 0..159, one q-row each, 512 thr; sums KS1=16
// partials) + Z2s packing (blocks 160..959).
// ---------------------------------------------------------------------------
__global__ __launch_bounds__(512) void smpz_kernel(const float* __restrict__ z2,
                                                   const float* __restrict__ Sp,
                                                   unsigned short* __restrict__ Atn2,
                                                   unsigned short* __restrict__ Z2s) {
    const int bid = blockIdx.x;
    const int t = threadIdx.x;
    if (bid < 160) {                          // ---- softmax role ----
        const int i = bid;
        const int wave = t >> 6, lane = t & 63;
        __shared__ float red2[8];
        f32x4 v[3];
        float s = 0.f;
#pragma unroll
        for (int jj = 0; jj < 3; ++jj) {
            int q4 = t + jj * 512;
            f32x4 r = (f32x4){0.f, 0.f, 0.f, 0.f};
            if (q4 < 1456) {
                f32x4 a = (f32x4){0.f, 0.f, 0.f, 0.f};
#pragma unroll
                for (int p = 0; p < KS1; ++p)
                    a += *(const f32x4*)(Sp + (size_t)p * (160 * JP_) + (size_t)i * JP_ + q4 * 4);
                a *= (1.0f / 5120.0f);
                bool pad_hi = (((q4 * 4) & 63) == 60);   // cols 61,62,63 of a band
#pragma unroll
                for (int e = 0; e < 4; ++e) {
                    bool ok = !(pad_hi && e > 0);
                    float x = ok ? __expf(a[e]) : 0.f;
                    r[e] = x;
                    s += x;
                }
            }
            v[jj] = r;
        }
#pragma unroll
        for (int off = 32; off >= 1; off >>= 1) s += __shfl_xor(s, off);
        if (lane == 0) red2[wave] = s;
        __syncthreads();
        float inv = 1.0f / (red2[0] + red2[1] + red2[2] + red2[3] +
                            red2[4] + red2[5] + red2[6] + red2[7]);
#pragma unroll
        for (int jj = 0; jj < 3; ++jj) {
            int q4 = t + jj * 512;
            if (q4 < 1456) {
                short4v u;
                u.x = (short)f2bf(v[jj].x * inv);
                u.y = (short)f2bf(v[jj].y * inv);
                u.z = (short)f2bf(v[jj].z * inv);
                u.w = (short)f2bf(v[jj].w * inv);
                *(short4v*)(Atn2 + ((size_t)(q4 >> 1) * 160 + i) * 8 + (q4 & 1) * 4) = u;
            }
        }
    } else {                                  // ---- Z2s-pack role ----
        int o = (bid - 160) * 512 + t;        // 0..409599
        int kw = o / 102400, r8 = o - kw * 102400;
        int e0 = r8 * 8;
        int w0 = e0 & 63, rowbase = e0 - w0;
        unsigned short v[8];
        if (w0 < 56 || kw == 0) {             // fast path: window fits in row
            const float* p = z2 + rowbase + w0 + kw;
#pragma unroll
            for (int s = 0; s < 8; ++s) v[s] = f2bf(p[s]);
        } else {                              // boundary: clamp at col 63
#pragma unroll
            for (int s = 0; s < 8; ++s) v[s] = f2bf(z2[rowbase + min(w0 + s + kw, 63)]);
        }
        *(short8*)(Z2s + (size_t)kw * NZ + e0) = *(short8*)v;
    }
}

// ---------------------------------------------------------------------------
// GEMM2: grid (KS2=16, 80) = 1280 blocks x 256 thr (5 blocks/CU = 20
// waves/CU, 2x the R10 TLP); tile 64(d) x 160(i), ~11-iter k-loop,
// DOUBLE-BUFFERED LDS (one barrier per k-iter); plain Op partial stores
// (no fences — R8/R13 lesson: agent-scope sync costs ~100us+ at scale).
// ---------------------------------------------------------------------------
__global__ __launch_bounds__(256) void gemm2_kernel(const unsigned short* __restrict__ Atn2,
                                                    const unsigned short* __restrict__ Z2s,
                                                    float* __restrict__ Op) {
    __shared__ short As[2][64 * 40];   // KV^T tile [d_local][jp_local], stride 40 (2-way, free)
    const int t = threadIdx.x;
    const int ksp = blockIdx.x;      // 0..15
    const int dt = blockIdx.y;       // 0..79
    const int dbase = dt * 64;
    const int it0 = (182 * ksp) >> 4;
    const int it1 = (182 * (ksp + 1)) >> 4;
    const int wave = t >> 6, lane = t & 63;
    const int mh = wave & 1, nh = wave >> 1;       // wave tile 32(d) x 80(i)
    const int l15 = lane & 15, q = lane >> 4;

    // staging geometry (one short8 per thread per k-iter)
    const int dl_s = t >> 2, jg_s = t & 3;
    const int d_s = dbase + dl_s;
    const unsigned du_s = (unsigned)d_s;
    const int c_s = du_s / 40u, rr_s = d_s - c_s * 40;
    const int kh_s = rr_s >> 2, kw_s = rr_s & 3;
    const int sbase = kw_s * NZ + c_s * 6400 + kh_s * W_;

    f32x4 acc[2][5];
#pragma unroll
    for (int m = 0; m < 2; ++m)
#pragma unroll
        for (int n = 0; n < 5; ++n) acc[m][n] = (f32x4){0.f, 0.f, 0.f, 0.f};

#define STAGE2(buf, itv) do {                                                  \
        int jp0_ = (itv) * 32 + jg_s * 8;                                      \
        int hk_ = jp0_ >> 6, wk0_ = jp0_ & 63;                                 \
        *(short8*)&As[buf][dl_s * 40 + jg_s * 8] =                             \
            *(const short8*)(Z2s + sbase + hk_ * W_ + wk0_);                   \
    } while (0)

    STAGE2(0, it0);
    for (int it = it0; it < it1; ++it) {
        int pb = (it - it0) & 1;
        __syncthreads();                       // As[pb] ready
        if (it + 1 < it1) STAGE2(pb ^ 1, it + 1);
        int k0 = it * 32;
        short8 af[2], bf[5];
#pragma unroll
        for (int m = 0; m < 2; ++m)
            af[m] = *(const short8*)&As[pb][(mh * 32 + m * 16 + l15) * 40 + q * 8];
        const unsigned short* Bb = Atn2 + ((size_t)((k0 >> 3) + q) * 160) * 8;
#pragma unroll
        for (int n = 0; n < 5; ++n)
            bf[n] = *(const short8*)(Bb + ((nh * 5 + n) * 16 + l15) * 8);
#pragma unroll
        for (int m = 0; m < 2; ++m)
#pragma unroll
            for (int n = 0; n < 5; ++n)
                acc[m][n] = __builtin_amdgcn_mfma_f32_16x16x32_bf16(af[m], bf[n], acc[m][n], 0, 0, 0);
    }
#undef STAGE2

    float* base = Op + (size_t)ksp * ((size_t)NZ);
#pragma unroll
    for (int m = 0; m < 2; ++m) {
        int d0 = dbase + mh * 32 + m * 16 + q * 4;
#pragma unroll
        for (int n = 0; n < 5; ++n) {
            int i = (nh * 5 + n) * 16 + l15;
#pragma unroll
            for (int r = 0; r < 4; ++r)
                base[(size_t)(d0 + r) * 160 + i] = acc[m][n][r];
        }
    }
}

// ---------------------------------------------------------------------------
// reduce: out[c][ih*10+kh][iw*4+kw] = sum_p Op[p][d*160+i]; vectorized x4
// ---------------------------------------------------------------------------
__global__ __launch_bounds__(256) void reduce_kernel(const float* __restrict__ Op,
                                                     float* __restrict__ out) {
    int tid = blockIdx.x * 256 + threadIdx.x;   // < 204800
    int f = tid * 4;
    f32x4 s = (f32x4){0.f, 0.f, 0.f, 0.f};
#pragma unroll
    for (int p = 0; p < KS2; ++p) s += *(const f32x4*)(Op + (size_t)p * NZ + f);
    int d = f / 160, i0 = f - d * 160;          // x4 block never straddles d
    int c = d / 40, rr = d - c * 40;
    int kh = rr >> 2, kw = rr & 3;
#pragma unroll
    for (int r = 0; r < 4; ++r) {
        int i = i0 + r;
        int ih = i >> 4, iw = i & 15;
        out[c * 6400 + (ih * KH_ + kh) * W_ + iw * KW_ + kw] = s[r];
    }
}

extern "C" void kernel_launch(void* const* d_in, const int* in_sizes, int n_in,
                              void* d_out, int out_size, void* d_ws, size_t ws_size,
                              hipStream_t stream) {
    const float* z1 = (const float*)d_in[0];
    const float* z2 = (const float*)d_in[1];
    float* out = (float*)d_out;

    char* w = (char*)d_ws;
    unsigned short* Qb2  = (unsigned short*)(w);                 // 1,638,400 B
    unsigned short* Z2s  = (unsigned short*)(w + 1638400);       // 6,553,600 B
    unsigned short* X    = (unsigned short*)(w + 8192000);       // 13,107,200 B
    unsigned short* Atn2 = (unsigned short*)(w + 21299200);      // 1,863,680 B
    float* Sp = (float*)(w + 23162880);                          // 59,637,760 B (16 partials)
    float* Op = (float*)(w + 82800640);                          // 52,428,800 B (16 partials)

    pack_kernel<<<3600, 256, 0, stream>>>(z1, z2, Qb2, X);
    gemm1_kernel<<<dim3(KS1, 92), 256, 0, stream>>>(Qb2, X, Sp);
    smpz_kernel<<<960, 512, 0, stream>>>(z2, Sp, Atn2, Z2s);
    gemm2_kernel<<<dim3(KS2, 80), 256, 0, stream>>>(Atn2, Z2s, Op);
    reduce_kernel<<<800, 256, 0, stream>>>(Op, out);
}

// Round 16
// 135.146 us; speedup vs baseline: 1.9285x; 1.0176x over previous
//
#include <hip/hip_runtime.h>

#define KH_   10
#define KW_   4
#define W_    64
#define K1_   5120       // C*KH*KW
#define WK_   61
#define JP_   5824       // 91*64
#define NZ    819200
#define KS1   8          // k-split gemm1 (chunk 640, 20 iters of 32; M-split x2)
#define KS2   8          // jp-split gemm2 (chunk ~23 iters of 32)

typedef __attribute__((ext_vector_type(8))) short short8;
typedef __attribute__((ext_vector_type(4))) short short4v;
typedef __attribute__((ext_vector_type(4))) float f32x4;

__device__ __forceinline__ unsigned short f2bf(float f) {
    unsigned int u = __float_as_uint(f);
    return (unsigned short)((u + 0x8000u) >> 16);
}

// ---------------------------------------------------------------------------
// pack: Qb2 (Q frag layout) + X (gemm1 B).  (identical to measured R10)
// ---------------------------------------------------------------------------
__global__ __launch_bounds__(256) void pack_kernel(const float* __restrict__ z1,
                                                   const float* __restrict__ z2,
                                                   unsigned short* __restrict__ Qb2,
                                                   unsigned short* __restrict__ X) {
    int tid = blockIdx.x * 256 + threadIdx.x;   // < 921600
    if (tid < 102400) {                       // --- Qb2 octs (frag layout) ---
        int ko = tid / 160, i = tid - ko * 160;
        int d0 = ko * 8;
        int c = d0 / 40, rr = d0 - c * 40;
        int kh0 = rr >> 2;                    // even
        int ih = i >> 4, iw = i & 15;
        int a0 = c * 6400 + (ih * KH_ + kh0) * W_ + iw * KW_;
        unsigned short v[8];
#pragma unroll
        for (int s = 0; s < 4; ++s) v[s] = f2bf(z1[a0 + s]);
#pragma unroll
        for (int s = 0; s < 4; ++s) v[4 + s] = f2bf(z1[a0 + W_ + s]);
        *(short8*)(Qb2 + (size_t)tid * 8) = *(short8*)v;
    } else {                                  // --- X octs ---
        int o = tid - 102400;                 // o = (c*100+h)*64 + w
        int w = o & 63, ch = o >> 6;
        int h = ch % 100;
        unsigned short v[8];
        if (w <= 60 && h < 99) {              // fast path: no clamping needed
            const float* p0 = z2 + ch * 64 + w;
#pragma unroll
            for (int s = 0; s < 4; ++s) v[s] = f2bf(p0[s]);
#pragma unroll
            for (int s = 0; s < 4; ++s) v[4 + s] = f2bf(p0[64 + s]);
        } else {                              // boundary path (w>60 or h==99)
            int ch2 = (h < 99) ? ch + 1 : ch;
#pragma unroll
            for (int s = 0; s < 4; ++s) v[s] = f2bf(z2[ch * 64 + min(w + s, 63)]);
#pragma unroll
            for (int s = 0; s < 4; ++s) v[4 + s] = f2bf(z2[ch2 * 64 + min(w + s, 63)]);
        }
        *(short8*)(X + (size_t)o * 8) = *(short8*)v;
    }
}

// ---------------------------------------------------------------------------
// GEMM1: no LDS, no barriers. grid (KS1=8, 92) = 736 blocks x 256 thr.
// Block tile 80(m) x 128(j) x 640(k); wave tile 80x32 (acc[5][2]).
// (identical to the measured 128.5us R10 version)
// ---------------------------------------------------------------------------
__global__ __launch_bounds__(256) void gemm1_kernel(const unsigned short* __restrict__ Qb2,
                                                    const unsigned short* __restrict__ X,
                                                    float* __restrict__ Sp) {
    const int t = threadIdx.x;
    const int ksp = blockIdx.x;      // 0..7
    const int by  = blockIdx.y;      // 0..91
    const int hkt = by >> 1;         // 0..45
    const int mhf = by & 1;          // row half (80 rows each)
    const int hk0 = hkt * 2;
    const int wave = t >> 6, lane = t & 63;
    const int nh = wave;             // 0..3: 32-col strip within 128
    const int l15 = lane & 15, q = lane >> 4;

    int band[2], wk[2];
#pragma unroll
    for (int n = 0; n < 2; ++n) {
        int jpn = nh * 32 + n * 16 + l15;
        band[n] = jpn >> 6;
        wk[n]   = jpn & 63;
    }
    int rowA[5];
#pragma unroll
    for (int b = 0; b < 5; ++b) rowA[b] = mhf * 80 + b * 16 + l15;

    f32x4 acc[5][2];
#pragma unroll
    for (int b = 0; b < 5; ++b)
#pragma unroll
        for (int n = 0; n < 2; ++n) acc[b][n] = (f32x4){0.f, 0.f, 0.f, 0.f};

    for (int it = 0; it < 20; ++it) {
        const unsigned short* Ab = Qb2 + ((size_t)(ksp * 80 + it * 4 + q) * 160) * 8;
        short8 af[5], bf[2];
#pragma unroll
        for (int b = 0; b < 5; ++b)
            af[b] = *(const short8*)(Ab + rowA[b] * 8);
        int d0 = ksp * 640 + it * 32 + q * 8;
        unsigned du = (unsigned)d0;
        int c = du / 40u, rr = d0 - c * 40;
        int kh0 = rr >> 2;           // even
        const unsigned short* Bb = X + ((size_t)(c * 100 + hk0 + kh0) * 64) * 8;
#pragma unroll
        for (int n = 0; n < 2; ++n)
            bf[n] = *(const short8*)(Bb + (band[n] * 64 + wk[n]) * 8);
#pragma unroll
        for (int b = 0; b < 5; ++b)
#pragma unroll
            for (int n = 0; n < 2; ++n)
                acc[b][n] = __builtin_amdgcn_mfma_f32_16x16x32_bf16(af[b], bf[n], acc[b][n], 0, 0, 0);
    }
    float* base = Sp + (size_t)ksp * (160 * JP_);
#pragma unroll
    for (int b = 0; b < 5; ++b) {
        int i0 = mhf * 80 + b * 16 + q * 4;
#pragma unroll
        for (int n = 0; n < 2; ++n) {
            int jg = hkt * 128 + nh * 32 + n * 16 + l15;
            if (jg < JP_) {
#pragma unroll
                for (int r = 0; r < 4; ++r)
                    base[(size_t)(i0 + r) * JP_ + jg] = acc[b][n][r];
            }
        }
    }
}

// ---------------------------------------------------------------------------
// smpz: softmax (blocks 0..159, one q-row each, 512 thr) + Z2s packing
// (blocks 160..959).  (identical to the measured 128.5us R10 version)
// ---------------------------------------------------------------------------
__global__ __launch_bounds__(512) void smpz_kernel(const float* __restrict__ z2,
                                                   const float* __restrict__ Sp,
                                                   unsigned short* __restrict__ Atn2,
                                                   unsigned short* __restrict__ Z2s) {
    const int bid = blockIdx.x;
    const int t = threadIdx.x;
    if (bid < 160) {                          // ---- softmax role ----
        const int i = bid;
        const int wave = t >> 6, lane = t & 63;
        __shared__ float red2[8];
        f32x4 v[3];
        float s = 0.f;
#pragma unroll
        for (int jj = 0; jj < 3; ++jj) {
            int q4 = t + jj * 512;
            f32x4 r = (f32x4){0.f, 0.f, 0.f, 0.f};
            if (q4 < 1456) {
                f32x4 a = (f32x4){0.f, 0.f, 0.f, 0.f};
#pragma unroll
                for (int p = 0; p < KS1; ++p)
                    a += *(const f32x4*)(Sp + (size_t)p * (160 * JP_) + (size_t)i * JP_ + q4 * 4);
                a *= (1.0f / 5120.0f);
                bool pad_hi = (((q4 * 4) & 63) == 60);   // cols 61,62,63 of a band
#pragma unroll
                for (int e = 0; e < 4; ++e) {
                    bool ok = !(pad_hi && e > 0);
                    float x = ok ? __expf(a[e]) : 0.f;
                    r[e] = x;
                    s += x;
                }
            }
            v[jj] = r;
        }
#pragma unroll
        for (int off = 32; off >= 1; off >>= 1) s += __shfl_xor(s, off);
        if (lane == 0) red2[wave] = s;
        __syncthreads();
        float inv = 1.0f / (red2[0] + red2[1] + red2[2] + red2[3] +
                            red2[4] + red2[5] + red2[6] + red2[7]);
#pragma unroll
        for (int jj = 0; jj < 3; ++jj) {
            int q4 = t + jj * 512;
            if (q4 < 1456) {
                short4v u;
                u.x = (short)f2bf(v[jj].x * inv);
                u.y = (short)f2bf(v[jj].y * inv);
                u.z = (short)f2bf(v[jj].z * inv);
                u.w = (short)f2bf(v[jj].w * inv);
                *(short4v*)(Atn2 + ((size_t)(q4 >> 1) * 160 + i) * 8 + (q4 & 1) * 4) = u;
            }
        }
    } else {                                  // ---- Z2s-pack role ----
        int o = (bid - 160) * 512 + t;        // 0..409599
        int kw = o / 102400, r8 = o - kw * 102400;
        int e0 = r8 * 8;
        int w0 = e0 & 63, rowbase = e0 - w0;
        unsigned short v[8];
        if (w0 < 56 || kw == 0) {             // fast path: window fits in row
            const float* p = z2 + rowbase + w0 + kw;
#pragma unroll
            for (int s = 0; s < 8; ++s) v[s] = f2bf(p[s]);
        } else {                              // boundary: clamp at col 63
#pragma unroll
            for (int s = 0; s < 8; ++s) v[s] = f2bf(z2[rowbase + min(w0 + s + kw, 63)]);
        }
        *(short8*)(Z2s + (size_t)kw * NZ + e0) = *(short8*)v;
    }
}

// ---------------------------------------------------------------------------
// GEMM2: NO LDS, NO BARRIERS (gemm1-style).  grid (KS2=8, 80) = 640 blocks.
// Key insight: the MFMA A-fragment is 8 bf16 contiguous along jp for one
// d-row, and jp0 = k0 + q*8 never crosses a 64-wide Z2s row (multiples of 8;
// 56+8=64).  So each lane loads af[m] DIRECTLY from Z2s with one global
// short8 load — value-identical to the old staged path (kw-clamp is baked
// into Z2s), same scatter pattern gemm1's A-loads already use.  Deletes the
// per-iter global->LDS->barrier round-trip that made every iteration wait
// on a full load latency (R13 attribution: gemm2 ~45-55us, the top stage).
// ---------------------------------------------------------------------------
__global__ __launch_bounds__(256) void gemm2_kernel(const unsigned short* __restrict__ Atn2,
                                                    const unsigned short* __restrict__ Z2s,
                                                    float* __restrict__ Op) {
    const int t = threadIdx.x;
    const int ksp = blockIdx.x;      // 0..7
    const int dt = blockIdx.y;       // 0..79
    const int dbase = dt * 64;
    const int it0 = (182 * ksp) >> 3;
    const int it1 = (182 * (ksp + 1)) >> 3;
    const int wave = t >> 6, lane = t & 63;
    const int mh = wave & 1, nh = wave >> 1;       // wave tile 32(d) x 80(i)
    const int l15 = lane & 15, q = lane >> 4;

    // per-lane A geometry: d-row base for each of the 2 m-fragments
    int abase[2];
#pragma unroll
    for (int m = 0; m < 2; ++m) {
        int d = dbase + mh * 32 + m * 16 + l15;
        unsigned du = (unsigned)d;
        int c = du / 40u, rr = d - c * 40;
        int kh = rr >> 2, kw = rr & 3;
        abase[m] = kw * NZ + c * 6400 + kh * W_;
    }

    f32x4 acc[2][5];
#pragma unroll
    for (int m = 0; m < 2; ++m)
#pragma unroll
        for (int n = 0; n < 5; ++n) acc[m][n] = (f32x4){0.f, 0.f, 0.f, 0.f};

    for (int it = it0; it < it1; ++it) {
        int k0 = it * 32;
        int jp0 = k0 + q * 8;
        int hk = jp0 >> 6, wk0 = jp0 & 63;   // never crosses a row (mult of 8)
        short8 af[2], bf[5];
#pragma unroll
        for (int m = 0; m < 2; ++m)
            af[m] = *(const short8*)(Z2s + abase[m] + hk * W_ + wk0);
        const unsigned short* Bb = Atn2 + ((size_t)((k0 >> 3) + q) * 160) * 8;
#pragma unroll
        for (int n = 0; n < 5; ++n)
            bf[n] = *(const short8*)(Bb + ((nh * 5 + n) * 16 + l15) * 8);
#pragma unroll
        for (int m = 0; m < 2; ++m)
#pragma unroll
            for (int n = 0; n < 5; ++n)
                acc[m][n] = __builtin_amdgcn_mfma_f32_16x16x32_bf16(af[m], bf[n], acc[m][n], 0, 0, 0);
    }

    float* base = Op + (size_t)ksp * ((size_t)NZ);
#pragma unroll
    for (int m = 0; m < 2; ++m) {
        int d0 = dbase + mh * 32 + m * 16 + q * 4;
#pragma unroll
        for (int n = 0; n < 5; ++n) {
            int i = (nh * 5 + n) * 16 + l15;
#pragma unroll
            for (int r = 0; r < 4; ++r)
                base[(size_t)(d0 + r) * 160 + i] = acc[m][n][r];
        }
    }
}

// ---------------------------------------------------------------------------
// reduce: out[c][ih*10+kh][iw*4+kw] = sum_p Op[p][d*160+i]; vectorized x4
// ---------------------------------------------------------------------------
__global__ __launch_bounds__(256) void reduce_kernel(const float* __restrict__ Op,
                                                     float* __restrict__ out) {
    int tid = blockIdx.x * 256 + threadIdx.x;   // < 204800
    int f = tid * 4;
    f32x4 s = (f32x4){0.f, 0.f, 0.f, 0.f};
#pragma unroll
    for (int p = 0; p < KS2; ++p) s += *(const f32x4*)(Op + (size_t)p * NZ + f);
    int d = f / 160, i0 = f - d * 160;          // x4 block never straddles d
    int c = d / 40, rr = d - c * 40;
    int kh = rr >> 2, kw = rr & 3;
#pragma unroll
    for (int r = 0; r < 4; ++r) {
        int i = i0 + r;
        int ih = i >> 4, iw = i & 15;
        out[c * 6400 + (ih * KH_ + kh) * W_ + iw * KW_ + kw] = s[r];
    }
}

extern "C" void kernel_launch(void* const* d_in, const int* in_sizes, int n_in,
                              void* d_out, int out_size, void* d_ws, size_t ws_size,
                              hipStream_t stream) {
    const float* z1 = (const float*)d_in[0];
    const float* z2 = (const float*)d_in[1];
    float* out = (float*)d_out;

    char* w = (char*)d_ws;
    unsigned short* Qb2  = (unsigned short*)(w);                 // 1,638,400 B
    unsigned short* Z2s  = (unsigned short*)(w + 1638400);       // 6,553,600 B
    unsigned short* X    = (unsigned short*)(w + 8192000);       // 13,107,200 B
    unsigned short* Atn2 = (unsigned short*)(w + 21299200);      // 1,863,680 B
    float* Sp = (float*)(w + 23162880);                          // 29,818,880 B (8 partials)
    float* Op = (float*)(w + 52981760);                          // 26,214,400 B (8 partials)

    pack_kernel<<<3600, 256, 0, stream>>>(z1, z2, Qb2, X);
    gemm1_kernel<<<dim3(KS1, 92), 256, 0, stream>>>(Qb2, X, Sp);
    smpz_kernel<<<960, 512, 0, stream>>>(z2, Sp, Atn2, Z2s);
    gemm2_kernel<<<dim3(KS2, 80), 256, 0, stream>>>(Atn2, Z2s, Op);
    reduce_kernel<<<800, 256, 0, stream>>>(Op, out);
}